// Round 4
// baseline (1269.852 us; speedup 1.0000x reference)
//
#include <hip/hip_runtime.h>
#include <stdint.h>

#define DIM 16
#define HID 128
#define TN  32
#define ROWF 132          // LDS row stride in floats (128 + 4 pad)
#define EPSF 1e-5f

// NaN-free tanh; |x| <= ~12 here (LN output bounded by sqrt(H))
__device__ __forceinline__ float safe_tanh(float x) {
    float a = fabsf(x);
    float e = __expf(2.0f * a);
    float t = 1.0f - 2.0f / (e + 1.0f);
    return copysignf(t, x);
}

// ================= CSR build + gather aggregation =========================
// cnt/offs/cursor layout: [0,N) = in-degree (by dst), [N,2N) = out-degree (by src)
// list: single array of 2E int2 entries {other_node, w_bits}; in-slots occupy
// [0,E), out-slots [E,2E) automatically via the scan.

__global__ void __launch_bounds__(256) count_kernel(
    const int* __restrict__ edges, int nEdges, int* __restrict__ cnt, int N)
{
    int e = blockIdx.x * 256 + threadIdx.x;
    if (e >= nEdges) return;
    int2 sd = ((const int2*)edges)[e];   // x=src, y=dst
    atomicAdd(&cnt[sd.y], 1);
    atomicAdd(&cnt[N + sd.x], 1);
}

__global__ void __launch_bounds__(256) block_sums_kernel(
    const int* __restrict__ in, int n, int* __restrict__ bsum)
{
    int i = blockIdx.x * 256 + threadIdx.x;
    int v = (i < n) ? in[i] : 0;
    #pragma unroll
    for (int d = 1; d < 64; d <<= 1) v += __shfl_xor(v, d);
    __shared__ int ws[4];
    if ((threadIdx.x & 63) == 0) ws[threadIdx.x >> 6] = v;
    __syncthreads();
    if (threadIdx.x == 0) bsum[blockIdx.x] = ws[0] + ws[1] + ws[2] + ws[3];
}

// exclusive scan of bsum in place; nb arbitrary (chunks of 1024)
__global__ void scan_bsums_kernel(int* __restrict__ bsum, int nb)
{
    __shared__ int s0[1024], s1[1024];
    int carry = 0;
    for (int base = 0; base < nb; base += 1024) {
        int orig[4];
        #pragma unroll
        for (int t = 0; t < 4; ++t) {
            int i = threadIdx.x + 256 * t;
            int v = (base + i < nb) ? bsum[base + i] : 0;
            s0[i] = v; orig[t] = v;
        }
        __syncthreads();
        int* src = s0; int* dst = s1;
        for (int d = 1; d < 1024; d <<= 1) {
            #pragma unroll
            for (int t = 0; t < 4; ++t) {
                int i = threadIdx.x + 256 * t;
                dst[i] = src[i] + (i >= d ? src[i - d] : 0);
            }
            __syncthreads();
            int* tmp = src; src = dst; dst = tmp;
        }
        #pragma unroll
        for (int t = 0; t < 4; ++t) {
            int i = threadIdx.x + 256 * t;
            if (base + i < nb) bsum[base + i] = carry + src[i] - orig[t];
        }
        int total = src[1023];
        __syncthreads();
        carry += total;
    }
}

__global__ void __launch_bounds__(256) scan_write_kernel(
    const int* __restrict__ in, int n, const int* __restrict__ bsum,
    int* __restrict__ out)
{
    int i = blockIdx.x * 256 + threadIdx.x;
    int v = (i < n) ? in[i] : 0;
    int lane = threadIdx.x & 63, wid = threadIdx.x >> 6;
    int x = v;
    #pragma unroll
    for (int d = 1; d < 64; d <<= 1) {
        int t = __shfl_up(x, d);
        if (lane >= d) x += t;
    }
    __shared__ int wsum[4], woff[4];
    if (lane == 63) wsum[wid] = x;
    __syncthreads();
    if (threadIdx.x == 0) {
        int r = 0;
        #pragma unroll
        for (int w = 0; w < 4; ++w) { woff[w] = r; r += wsum[w]; }
    }
    __syncthreads();
    if (i < n) out[i] = bsum[blockIdx.x] + woff[wid] + x - v;
}

__global__ void __launch_bounds__(256) fill_kernel(
    const int* __restrict__ edges, const float* __restrict__ ew, int nEdges,
    int* __restrict__ cursor, int N, int2* __restrict__ list)
{
    int e = blockIdx.x * 256 + threadIdx.x;
    if (e >= nEdges) return;
    int2 sd = ((const int2*)edges)[e];
    int wb = __float_as_int(ew[e]);
    int p1 = atomicAdd(&cursor[sd.y], 1);
    list[p1] = make_int2(sd.x, wb);          // in-edge of dst: neighbor=src
    int p2 = atomicAdd(&cursor[N + sd.x], 1);
    list[p2] = make_int2(sd.y, wb);          // out-edge of src: neighbor=dst
}

// one wave per node: lanes = 4 entry-groups x 16 cols
__global__ void __launch_bounds__(256) aggregate_kernel(
    const float* __restrict__ nodes, const int2* __restrict__ list,
    const int* __restrict__ offs, const int* __restrict__ cursor,
    float* __restrict__ agg_in, float* __restrict__ agg_out, int N)
{
    int n = blockIdx.x * 4 + (threadIdx.x >> 6);
    if (n >= N) return;
    int lane = threadIdx.x & 63;
    int g = lane >> 4, c = lane & 15;

    float a_in = 0.f, a_out = 0.f;
    int s = offs[n], e2 = cursor[n];
    for (int j = s + g; j < e2; j += 4) {
        int2 ent = list[j];
        a_in += __int_as_float(ent.y) * nodes[ent.x * DIM + c];
    }
    s = offs[N + n]; e2 = cursor[N + n];
    for (int j = s + g; j < e2; j += 4) {
        int2 ent = list[j];
        a_out += __int_as_float(ent.y) * nodes[ent.x * DIM + c];
    }
    a_in  += __shfl_xor(a_in, 16);  a_in  += __shfl_xor(a_in, 32);
    a_out += __shfl_xor(a_out, 16); a_out += __shfl_xor(a_out, 32);
    if (g == 0) {
        agg_in[n * DIM + c]  = a_in;
        agg_out[n * DIM + c] = a_out;
    }
}

// ---------------- fallback: direct atomic scatter -------------------------
__global__ void __launch_bounds__(256) edge_scatter_kernel(
    const float* __restrict__ nodes, const int* __restrict__ edges,
    const float* __restrict__ ew, float* __restrict__ agg_in,
    float* __restrict__ agg_out, int nEdges)
{
    int gid = blockIdx.x * 256 + threadIdx.x;
    int e = gid >> 4;
    if (e >= nEdges) return;
    int c = gid & 15;
    int src = edges[2 * e];
    int dst = edges[2 * e + 1];
    float w  = ew[e];
    atomicAdd(&agg_in[dst * DIM + c], nodes[src * DIM + c] * w);
    atomicAdd(&agg_out[src * DIM + c], nodes[dst * DIM + c] * w);
}

// ---------------- Phase 2: fused 4-layer MLP ------------------------------
template<int K>
__device__ __forceinline__ void dense_ln_tanh(
    const float* __restrict__ W, const float* __restrict__ bias,
    const float* __restrict__ g, const float* __restrict__ be,
    float (&X)[TN][ROWF], float* mean_s, float* rstd_s, int tid)
{
    const int c0 = (tid & 31) * 4;   // column group
    const int n0 = (tid >> 5) * 4;   // node group
    float acc[4][4];
    {
        float4 bv = *(const float4*)(bias + c0);
        #pragma unroll
        for (int i = 0; i < 4; ++i) {
            acc[i][0] = bv.x; acc[i][1] = bv.y; acc[i][2] = bv.z; acc[i][3] = bv.w;
        }
    }

    #pragma unroll 2
    for (int k = 0; k < K; k += 4) {
        float xr[4][4];
        #pragma unroll
        for (int i = 0; i < 4; ++i) {
            float4 t = *(const float4*)&X[n0 + i][k];
            xr[i][0] = t.x; xr[i][1] = t.y; xr[i][2] = t.z; xr[i][3] = t.w;
        }
        float w[4][4];
        #pragma unroll
        for (int kk = 0; kk < 4; ++kk) {
            float4 t = *(const float4*)(W + (k + kk) * HID + c0);
            w[kk][0] = t.x; w[kk][1] = t.y; w[kk][2] = t.z; w[kk][3] = t.w;
        }
        #pragma unroll
        for (int kk = 0; kk < 4; ++kk)
            #pragma unroll
            for (int i = 0; i < 4; ++i)
                #pragma unroll
                for (int j = 0; j < 4; ++j) acc[i][j] += xr[i][kk] * w[kk][j];
    }
    __syncthreads();
    #pragma unroll
    for (int i = 0; i < 4; ++i)
        *(float4*)&X[n0 + i][c0] = make_float4(acc[i][0], acc[i][1], acc[i][2], acc[i][3]);
    __syncthreads();

    {
        const int n = tid >> 3;
        const int s = tid & 7;
        float sum = 0.f, sq = 0.f;
        #pragma unroll
        for (int i = 0; i < 16; ++i) {
            float v = X[n][s * 16 + i];
            sum += v; sq += v * v;
        }
        #pragma unroll
        for (int m = 1; m <= 4; m <<= 1) {
            sum += __shfl_xor(sum, m);
            sq  += __shfl_xor(sq, m);
        }
        if (s == 0) {
            float mean = sum * (1.0f / HID);
            float var  = sq * (1.0f / HID) - mean * mean;
            mean_s[n] = mean;
            rstd_s[n] = rsqrtf(fmaxf(var, 0.0f) + EPSF);
        }
    }
    __syncthreads();

    {
        float4 gv  = *(const float4*)(g + c0);
        float4 bev = *(const float4*)(be + c0);
        float gr[4]  = {gv.x, gv.y, gv.z, gv.w};
        float ber[4] = {bev.x, bev.y, bev.z, bev.w};
        #pragma unroll
        for (int i = 0; i < 4; ++i) {
            float m = mean_s[n0 + i], r = rstd_s[n0 + i];
            #pragma unroll
            for (int j = 0; j < 4; ++j)
                acc[i][j] = safe_tanh((acc[i][j] - m) * r * gr[j] + ber[j]);
            *(float4*)&X[n0 + i][c0] = make_float4(acc[i][0], acc[i][1], acc[i][2], acc[i][3]);
        }
    }
    __syncthreads();
}

__global__ void __launch_bounds__(256) mlp_kernel(
    const float* __restrict__ agg_in, const float* __restrict__ agg_out,
    const float* __restrict__ nodes,
    const float* __restrict__ W1, const float* __restrict__ b1, const float* __restrict__ g1, const float* __restrict__ be1,
    const float* __restrict__ W2, const float* __restrict__ b2, const float* __restrict__ g2, const float* __restrict__ be2,
    const float* __restrict__ W3, const float* __restrict__ b3, const float* __restrict__ g3, const float* __restrict__ be3,
    const float* __restrict__ W4, const float* __restrict__ b4, const float* __restrict__ g4, const float* __restrict__ be4,
    float* __restrict__ out, int nNodes)
{
    __shared__ float X[TN][ROWF];
    __shared__ float mean_s[TN], rstd_s[TN];

    const int tid = threadIdx.x;
    const int node0 = blockIdx.x * TN;
    if (node0 >= nNodes) return;

    for (int i = tid; i < TN * 48; i += 256) {
        int n = i / 48, c = i - n * 48;
        int gn = node0 + n;
        float v;
        if (c < 16)      v = agg_in[gn * DIM + c];
        else if (c < 32) v = agg_out[gn * DIM + (c - 16)];
        else             v = nodes[gn * DIM + (c - 32)];
        X[n][c] = v;
    }
    __syncthreads();

    dense_ln_tanh<48>(W1, b1, g1, be1, X, mean_s, rstd_s, tid);
    dense_ln_tanh<128>(W2, b2, g2, be2, X, mean_s, rstd_s, tid);
    dense_ln_tanh<128>(W3, b3, g3, be3, X, mean_s, rstd_s, tid);

    {
        const int c2 = tid & 15;
        const int nn = tid >> 4;
        float aA = b4[c2];
        float aB = aA;
        #pragma unroll 4
        for (int k = 0; k < HID; k += 4) {
            float4 xA = *(const float4*)&X[nn][k];
            float4 xB = *(const float4*)&X[nn + 16][k];
            float xa[4] = {xA.x, xA.y, xA.z, xA.w};
            float xb[4] = {xB.x, xB.y, xB.z, xB.w};
            #pragma unroll
            for (int kk = 0; kk < 4; ++kk) {
                float w = W4[(k + kk) * DIM + c2];
                aA += xa[kk] * w;
                aB += xb[kk] * w;
            }
        }
        float sA = aA, qA = aA * aA, sB = aB, qB = aB * aB;
        #pragma unroll
        for (int m = 1; m <= 8; m <<= 1) {
            sA += __shfl_xor(sA, m); qA += __shfl_xor(qA, m);
            sB += __shfl_xor(sB, m); qB += __shfl_xor(qB, m);
        }
        float g4v = g4[c2], be4v = be4[c2];
        float mA = sA * (1.0f / DIM), vA = fmaxf(qA * (1.0f / DIM) - mA * mA, 0.0f);
        float mB = sB * (1.0f / DIM), vB = fmaxf(qB * (1.0f / DIM) - mB * mB, 0.0f);
        float oA = safe_tanh((aA - mA) * rsqrtf(vA + EPSF) * g4v + be4v);
        float oB = safe_tanh((aB - mB) * rsqrtf(vB + EPSF) * g4v + be4v);
        out[(size_t)(node0 + nn) * DIM + c2]      = oA;
        out[(size_t)(node0 + nn + 16) * DIM + c2] = oB;
    }
}

extern "C" void kernel_launch(void* const* d_in, const int* in_sizes, int n_in,
                              void* d_out, int out_size, void* d_ws, size_t ws_size,
                              hipStream_t stream)
{
    const float* nodes = (const float*)d_in[0];
    const int*   edges = (const int*)d_in[1];
    const float* ew    = (const float*)d_in[2];
    const float *W1 = (const float*)d_in[3],  *b1 = (const float*)d_in[4],
                *g1 = (const float*)d_in[5],  *be1 = (const float*)d_in[6];
    const float *W2 = (const float*)d_in[7],  *b2 = (const float*)d_in[8],
                *g2 = (const float*)d_in[9],  *be2 = (const float*)d_in[10];
    const float *W3 = (const float*)d_in[11], *b3 = (const float*)d_in[12],
                *g3 = (const float*)d_in[13], *be3 = (const float*)d_in[14];
    const float *W4 = (const float*)d_in[15], *b4 = (const float*)d_in[16],
                *g4 = (const float*)d_in[17], *be4 = (const float*)d_in[18];

    const int N = in_sizes[0] / DIM;     // 100000
    const int E = in_sizes[2];           // 3200000
    const int nScan = 2 * N;
    const int nbScan = (nScan + 255) / 256;

    // workspace layout (256B aligned)
    auto align256 = [](size_t x) { return (x + 255) & ~(size_t)255; };
    size_t o = 0;
    size_t agg_in_off  = o; o = align256(o + (size_t)N * DIM * 4);
    size_t agg_out_off = o; o = align256(o + (size_t)N * DIM * 4);
    size_t cnt_off     = o; o = align256(o + (size_t)nScan * 4);
    size_t offs_off    = o; o = align256(o + (size_t)nScan * 4);
    size_t cursor_off  = o; o = align256(o + (size_t)nScan * 4);
    size_t bsum_off    = o; o = align256(o + (size_t)nbScan * 4);
    size_t list_off    = o; o = align256(o + (size_t)2 * E * 8);
    size_t need = o;

    float* agg_in  = (float*)((char*)d_ws + agg_in_off);
    float* agg_out = (float*)((char*)d_ws + agg_out_off);

    if (ws_size >= need) {
        int*  cnt    = (int*)((char*)d_ws + cnt_off);
        int*  offs   = (int*)((char*)d_ws + offs_off);
        int*  cursor = (int*)((char*)d_ws + cursor_off);
        int*  bsum   = (int*)((char*)d_ws + bsum_off);
        int2* list   = (int2*)((char*)d_ws + list_off);

        hipMemsetAsync(cnt, 0, (size_t)nScan * 4, stream);

        int egrid = (E + 255) / 256;
        count_kernel<<<egrid, 256, 0, stream>>>(edges, E, cnt, N);
        block_sums_kernel<<<nbScan, 256, 0, stream>>>(cnt, nScan, bsum);
        scan_bsums_kernel<<<1, 256, 0, stream>>>(bsum, nbScan);
        scan_write_kernel<<<nbScan, 256, 0, stream>>>(cnt, nScan, bsum, offs);
        hipMemcpyAsync(cursor, offs, (size_t)nScan * 4, hipMemcpyDeviceToDevice, stream);
        fill_kernel<<<egrid, 256, 0, stream>>>(edges, ew, E, cursor, N, list);
        int agrid = (N + 3) / 4;
        aggregate_kernel<<<agrid, 256, 0, stream>>>(nodes, list, offs, cursor,
                                                    agg_in, agg_out, N);
    } else {
        // fallback: direct atomic scatter (proven path)
        hipMemsetAsync(d_ws, 0, (size_t)2 * N * DIM * 4, stream);
        long long ethreads = (long long)E * 16;
        int egrid2 = (int)((ethreads + 255) / 256);
        edge_scatter_kernel<<<egrid2, 256, 0, stream>>>(nodes, edges, ew,
                                                        agg_in, agg_out, E);
    }

    int mgrid = (N + TN - 1) / TN;
    mlp_kernel<<<mgrid, 256, 0, stream>>>(agg_in, agg_out, nodes,
        W1, b1, g1, be1, W2, b2, g2, be2, W3, b3, g3, be3, W4, b4, g4, be4,
        (float*)d_out, N);
}

// Round 5
// 576.199 us; speedup vs baseline: 2.2038x; 2.2038x over previous
//
#include <hip/hip_runtime.h>
#include <stdint.h>

#define DIM 16
#define HID 128
#define TN  64            // nodes per block
#define ROWF 132          // LDS row stride in floats (128 + 4 pad)
#define EPSF 1e-5f

// NaN-free tanh; |x| <= ~12 here (LN output bounded by sqrt(H))
__device__ __forceinline__ float safe_tanh(float x) {
    float a = fabsf(x);
    float e = __expf(2.0f * a);
    float t = 1.0f - 2.0f / (e + 1.0f);
    return copysignf(t, x);
}

// ---------------- Phase 1: edge scatter-add (proven round-3 path) ---------
// 16 threads per edge (one per feature component). 102.4M fire-and-forget
// dword atomics at ~328 G/s = memory-side atomic ceiling.
__global__ void __launch_bounds__(256) edge_scatter_kernel(
    const float* __restrict__ nodes, const int* __restrict__ edges,
    const float* __restrict__ ew, float* __restrict__ agg_in,
    float* __restrict__ agg_out, int nEdges)
{
    int gid = blockIdx.x * 256 + threadIdx.x;
    int e = gid >> 4;
    if (e >= nEdges) return;
    int c = gid & 15;
    int src = edges[2 * e];
    int dst = edges[2 * e + 1];
    float w  = ew[e];
    float vs = nodes[src * DIM + c];
    float vd = nodes[dst * DIM + c];
    atomicAdd(&agg_in[dst * DIM + c], vs * w);   // agg_in[dst] += nodes[src]*w
    atomicAdd(&agg_out[src * DIM + c], vd * w);  // agg_out[src] += nodes[dst]*w
}

// ---------------- Phase 2: fused 4-layer MLP ------------------------------
// Block: 256 threads, 64-node tile. Thread owns 8 nodes x 4 cols.
// LN stats from accumulator registers via 32-lane shuffles (threads sharing
// the same 8 rows are exactly one aligned 32-lane half-wave).
template<int K>
__device__ __forceinline__ void dense_ln_tanh(
    const float* __restrict__ W, const float* __restrict__ bias,
    const float* __restrict__ g, const float* __restrict__ be,
    float (&X)[TN][ROWF], int tid)
{
    const int c0 = (tid & 31) * 4;   // column group: lanes 0..31 cover 128 cols
    const int n0 = (tid >> 5) * 8;   // row group: 8 rows per thread
    float acc[8][4];
    {
        float4 bv = *(const float4*)(bias + c0);
        #pragma unroll
        for (int i = 0; i < 8; ++i) {
            acc[i][0] = bv.x; acc[i][1] = bv.y; acc[i][2] = bv.z; acc[i][3] = bv.w;
        }
    }

    #pragma unroll 2
    for (int k = 0; k < K; k += 4) {
        float xr[8][4];
        #pragma unroll
        for (int i = 0; i < 8; ++i) {
            float4 t = *(const float4*)&X[n0 + i][k];
            xr[i][0] = t.x; xr[i][1] = t.y; xr[i][2] = t.z; xr[i][3] = t.w;
        }
        float w[4][4];
        #pragma unroll
        for (int kk = 0; kk < 4; ++kk) {
            float4 t = *(const float4*)(W + (k + kk) * HID + c0);
            w[kk][0] = t.x; w[kk][1] = t.y; w[kk][2] = t.z; w[kk][3] = t.w;
        }
        #pragma unroll
        for (int kk = 0; kk < 4; ++kk)
            #pragma unroll
            for (int i = 0; i < 8; ++i)
                #pragma unroll
                for (int j = 0; j < 4; ++j) acc[i][j] += xr[i][kk] * w[kk][j];
    }

    // per-row partial sums from registers, reduce across the 32-lane half
    float s[8], q[8];
    #pragma unroll
    for (int i = 0; i < 8; ++i) {
        s[i] = acc[i][0] + acc[i][1] + acc[i][2] + acc[i][3];
        q[i] = acc[i][0]*acc[i][0] + acc[i][1]*acc[i][1]
             + acc[i][2]*acc[i][2] + acc[i][3]*acc[i][3];
    }
    #pragma unroll
    for (int m = 1; m <= 16; m <<= 1) {
        #pragma unroll
        for (int i = 0; i < 8; ++i) {
            s[i] += __shfl_xor(s[i], m);
            q[i] += __shfl_xor(q[i], m);
        }
    }

    float4 gv  = *(const float4*)(g + c0);
    float4 bev = *(const float4*)(be + c0);
    float gr[4]  = {gv.x, gv.y, gv.z, gv.w};
    float ber[4] = {bev.x, bev.y, bev.z, bev.w};

    __syncthreads();   // all X reads of this layer complete before overwrite
    #pragma unroll
    for (int i = 0; i < 8; ++i) {
        float mean = s[i] * (1.0f / HID);
        float var  = fmaxf(q[i] * (1.0f / HID) - mean * mean, 0.0f);
        float r = rsqrtf(var + EPSF);
        float o[4];
        #pragma unroll
        for (int j = 0; j < 4; ++j)
            o[j] = safe_tanh((acc[i][j] - mean) * r * gr[j] + ber[j]);
        *(float4*)&X[n0 + i][c0] = make_float4(o[0], o[1], o[2], o[3]);
    }
    __syncthreads();
}

__global__ void __launch_bounds__(256, 3) mlp_kernel(
    const float* __restrict__ agg_in, const float* __restrict__ agg_out,
    const float* __restrict__ nodes,
    const float* __restrict__ W1, const float* __restrict__ b1, const float* __restrict__ g1, const float* __restrict__ be1,
    const float* __restrict__ W2, const float* __restrict__ b2, const float* __restrict__ g2, const float* __restrict__ be2,
    const float* __restrict__ W3, const float* __restrict__ b3, const float* __restrict__ g3, const float* __restrict__ be3,
    const float* __restrict__ W4, const float* __restrict__ b4, const float* __restrict__ g4, const float* __restrict__ be4,
    float* __restrict__ out, int nNodes)
{
    __shared__ float X[TN][ROWF];

    const int tid = threadIdx.x;
    const int node0 = blockIdx.x * TN;

    // stage x = concat(agg_in, agg_out, nodes): 64 rows x 12 float4
    for (int i = tid; i < TN * 12; i += 256) {
        int n = i / 12, c4 = i - n * 12;
        int gn = node0 + n;
        float4 v = make_float4(0.f, 0.f, 0.f, 0.f);
        if (gn < nNodes) {
            if (c4 < 4)      v = *(const float4*)(agg_in  + gn * DIM + c4 * 4);
            else if (c4 < 8) v = *(const float4*)(agg_out + gn * DIM + (c4 - 4) * 4);
            else             v = *(const float4*)(nodes   + gn * DIM + (c4 - 8) * 4);
        }
        *(float4*)&X[n][c4 * 4] = v;
    }
    __syncthreads();

    dense_ln_tanh<48>(W1, b1, g1, be1, X, tid);
    dense_ln_tanh<128>(W2, b2, g2, be2, X, tid);
    dense_ln_tanh<128>(W3, b3, g3, be3, X, tid);

    // Layer 4: 128 -> 16, LN over 16, tanh, store fp32
    {
        const int c2 = tid & 15;
        const int nb = tid >> 4;   // 0..15; handles nodes nb + {0,16,32,48}
        float a[4];
        {
            float bv = b4[c2];
            #pragma unroll
            for (int t = 0; t < 4; ++t) a[t] = bv;
        }
        #pragma unroll 2
        for (int k = 0; k < HID; k += 4) {
            float w[4];
            #pragma unroll
            for (int kk = 0; kk < 4; ++kk) w[kk] = W4[(k + kk) * DIM + c2];
            #pragma unroll
            for (int t = 0; t < 4; ++t) {
                float4 x = *(const float4*)&X[nb + 16 * t][k];
                a[t] += x.x * w[0] + x.y * w[1] + x.z * w[2] + x.w * w[3];
            }
        }
        float s[4], q[4];
        #pragma unroll
        for (int t = 0; t < 4; ++t) { s[t] = a[t]; q[t] = a[t] * a[t]; }
        #pragma unroll
        for (int m = 1; m <= 8; m <<= 1) {
            #pragma unroll
            for (int t = 0; t < 4; ++t) {
                s[t] += __shfl_xor(s[t], m);
                q[t] += __shfl_xor(q[t], m);
            }
        }
        float g4v = g4[c2], be4v = be4[c2];
        #pragma unroll
        for (int t = 0; t < 4; ++t) {
            int node = node0 + nb + 16 * t;
            if (node < nNodes) {
                float mean = s[t] * (1.0f / DIM);
                float var  = fmaxf(q[t] * (1.0f / DIM) - mean * mean, 0.0f);
                float o = safe_tanh((a[t] - mean) * rsqrtf(var + EPSF) * g4v + be4v);
                out[(size_t)node * DIM + c2] = o;
            }
        }
    }
}

extern "C" void kernel_launch(void* const* d_in, const int* in_sizes, int n_in,
                              void* d_out, int out_size, void* d_ws, size_t ws_size,
                              hipStream_t stream)
{
    const float* nodes = (const float*)d_in[0];
    const int*   edges = (const int*)d_in[1];
    const float* ew    = (const float*)d_in[2];
    const float *W1 = (const float*)d_in[3],  *b1 = (const float*)d_in[4],
                *g1 = (const float*)d_in[5],  *be1 = (const float*)d_in[6];
    const float *W2 = (const float*)d_in[7],  *b2 = (const float*)d_in[8],
                *g2 = (const float*)d_in[9],  *be2 = (const float*)d_in[10];
    const float *W3 = (const float*)d_in[11], *b3 = (const float*)d_in[12],
                *g3 = (const float*)d_in[13], *be3 = (const float*)d_in[14];
    const float *W4 = (const float*)d_in[15], *b4 = (const float*)d_in[16],
                *g4 = (const float*)d_in[17], *be4 = (const float*)d_in[18];

    const int N = in_sizes[0] / DIM;     // 100000
    const int E = in_sizes[2];           // 3200000

    float* agg_in  = (float*)d_ws;
    float* agg_out = agg_in + (size_t)N * DIM;

    hipMemsetAsync(d_ws, 0, (size_t)2 * N * DIM * sizeof(float), stream);

    long long ethreads = (long long)E * 16;
    int egrid = (int)((ethreads + 255) / 256);
    edge_scatter_kernel<<<egrid, 256, 0, stream>>>(nodes, edges, ew,
                                                   agg_in, agg_out, E);

    int mgrid = (N + TN - 1) / TN;
    mlp_kernel<<<mgrid, 256, 0, stream>>>(agg_in, agg_out, nodes,
        W1, b1, g1, be1, W2, b2, g2, be2, W3, b3, g3, be3, W4, b4, g4, be4,
        (float*)d_out, N);
}